// Round 12
// baseline (31920.422 us; speedup 1.0000x reference)
//
#include <hip/hip_runtime.h>

#define HDIM 96
#define G4   384
#define LSEQ 32768
#define BATCH 8
#define TCH   1024
#define NCH   (LSEQ / TCH)

#define L2E  1.4426950408889634f
#define SNEG (-L2E)        /* sigmoid gates: exp(-x) = exp2(SNEG*x) */
#define SPOS (2.0f * L2E)  /* tanh gates:    exp(2x) = exp2(SPOS*x) */

typedef float v2f __attribute__((ext_vector_type(2)));
#define FMA2(a,b,c) __builtin_elementwise_fma((a),(b),(c))
#define SPL(V,I)    __builtin_shufflevector((V),(V),(I),(I))

// DPP helpers (VALU pipe, zero DS usage).
#define DPPSTEP(v, CTRL) { \
    int t_ = __builtin_amdgcn_update_dpp(0, __float_as_int(v), CTRL, 0xF, 0xF, true); \
    v += __int_as_float(t_); }
#define DPPADDV(u, v, CTRL) { \
    int t_ = __builtin_amdgcn_update_dpp(0, __float_as_int(v), CTRL, 0xF, 0xF, true); \
    u += __int_as_float(t_); }

// quad_perm broadcast: all lanes of each quad read quad-lane L of src.
#define QBCAST(DST, SRCI, CTRL) \
    float DST = __int_as_float(__builtin_amdgcn_update_dpp(0, (SRCI), (CTRL), 0xF, 0xF, true));

// Lite barrier: LDS ordering only; global ops stay in flight.
#define BARL() asm volatile("s_waitcnt lgkmcnt(0)\n\ts_barrier" ::: "memory")

#define PIN4x3(A,B,C) asm volatile("" : \
  "+v"(A.x),"+v"(A.y),"+v"(A.z),"+v"(A.w), \
  "+v"(B.x),"+v"(B.y),"+v"(B.z),"+v"(B.w), \
  "+v"(C.x),"+v"(C.y),"+v"(C.z),"+v"(C.w));

#define SC4(V, S) { V.x *= (S); V.y *= (S); V.z *= (S); V.w *= (S); }

// Weights as v2f column-pairs (cols {2j,2j+1}), pre-scaled per gate.
// Used via SPL (VOP3P op_sel splat) in packed dual-sequence FMAs.
#define WLOADPIN_P(W) \
    const float4* pI = reinterpret_cast<const float4*>((W) + (size_t)e        * HDIM + 12*s); \
    const float4* pF = reinterpret_cast<const float4*>((W) + (size_t)(96 + e) * HDIM + 12*s); \
    const float4* pG = reinterpret_cast<const float4*>((W) + (size_t)(192+ e) * HDIM + 12*s); \
    const float4* pO = reinterpret_cast<const float4*>((W) + (size_t)(288+ e) * HDIM + 12*s); \
    float4 tI0=pI[0], tI1=pI[1], tI2=pI[2]; \
    float4 tF0=pF[0], tF1=pF[1], tF2=pF[2]; \
    float4 tG0=pG[0], tG1=pG[1], tG2=pG[2]; \
    float4 tO0=pO[0], tO1=pO[1], tO2=pO[2]; \
    SC4(tI0,SNEG) SC4(tI1,SNEG) SC4(tI2,SNEG) \
    SC4(tF0,SNEG) SC4(tF1,SNEG) SC4(tF2,SNEG) \
    SC4(tG0,SPOS) SC4(tG1,SPOS) SC4(tG2,SPOS) \
    SC4(tO0,SNEG) SC4(tO1,SNEG) SC4(tO2,SNEG) \
    v2f wI_0={tI0.x,tI0.y}, wI_1={tI0.z,tI0.w}, wI_2={tI1.x,tI1.y}, \
        wI_3={tI1.z,tI1.w}, wI_4={tI2.x,tI2.y}, wI_5={tI2.z,tI2.w}; \
    v2f wF_0={tF0.x,tF0.y}, wF_1={tF0.z,tF0.w}, wF_2={tF1.x,tF1.y}, \
        wF_3={tF1.z,tF1.w}, wF_4={tF2.x,tF2.y}, wF_5={tF2.z,tF2.w}; \
    v2f wG_0={tG0.x,tG0.y}, wG_1={tG0.z,tG0.w}, wG_2={tG1.x,tG1.y}, \
        wG_3={tG1.z,tG1.w}, wG_4={tG2.x,tG2.y}, wG_5={tG2.z,tG2.w}; \
    v2f wO_0={tO0.x,tO0.y}, wO_1={tO0.z,tO0.w}, wO_2={tO1.x,tO1.y}, \
        wO_3={tO1.z,tO1.w}, wO_4={tO2.x,tO2.y}, wO_5={tO2.z,tO2.w}; \
    asm volatile("" : "+v"(wI_0),"+v"(wI_1),"+v"(wI_2),"+v"(wI_3),"+v"(wI_4),"+v"(wI_5), \
                      "+v"(wF_0),"+v"(wF_1),"+v"(wF_2),"+v"(wF_3),"+v"(wF_4),"+v"(wF_5)); \
    asm volatile("" : "+v"(wG_0),"+v"(wG_1),"+v"(wG_2),"+v"(wG_3),"+v"(wG_4),"+v"(wG_5), \
                      "+v"(wO_0),"+v"(wO_1),"+v"(wO_2),"+v"(wO_3),"+v"(wO_4),"+v"(wO_5));

// One column of the packed dual MV: 4 gate pk-FMAs. CV = pair reg (c>>1),
// IDX = c&1 (op_sel splat). HP = {hA[c], hB[c]}.
#define MVPC(CV, IDX, HP) \
  giP = FMA2(SPL(wI_##CV,IDX), HP, giP); \
  gfP = FMA2(SPL(wF_##CV,IDX), HP, gfP); \
  ggP = FMA2(SPL(wG_##CV,IDX), HP, ggP); \
  goP = FMA2(SPL(wO_##CV,IDX), HP, goP);

#define MVALL() \
    MVPC(0,0,h_0) MVPC(0,1,h_1) MVPC(1,0,h_2) MVPC(1,1,h_3) \
    MVPC(2,0,h_4) MVPC(2,1,h_5) MVPC(3,0,h_6) MVPC(3,1,h_7) \
    MVPC(4,0,h_8) MVPC(4,1,h_9) MVPC(5,0,h_10) MVPC(5,1,h_11)

#define HUNPACK() \
    v2f h_0={hq0.x,hq0.y}, h_1={hq0.z,hq0.w}, h_2={hq1.x,hq1.y}, h_3={hq1.z,hq1.w}, \
        h_4={hq2.x,hq2.y}, h_5={hq2.z,hq2.w}, h_6={hq3.x,hq3.y}, h_7={hq3.z,hq3.w}, \
        h_8={hq4.x,hq4.y}, h_9={hq4.z,hq4.w}, h_10={hq5.x,hq5.y}, h_11={hq5.z,hq5.w};

// Dual mirror-symmetric transposing-butterfly tail, A/B interleaved.
// Per-sequence math bitwise-identical to R9's verified tail.
#define GT2(STA) \
    float uAA = (tsel & 1) ? gfA : giA,  vAA = (tsel & 1) ? giA : gfA; \
    float uAB = (tsel & 1) ? gfB : giB,  vAB = (tsel & 1) ? giB : gfB; \
    float uBA = (tsel & 1) ? goA : ggA,  vBA = (tsel & 1) ? ggA : goA; \
    float uBB = (tsel & 1) ? goB : ggB,  vBB = (tsel & 1) ? ggB : goB; \
    DPPADDV(uAA, vAA, 0xB1)  DPPADDV(uAB, vAB, 0xB1) \
    DPPADDV(uBA, vBA, 0xB1)  DPPADDV(uBB, vBB, 0xB1) \
    float uCA = (tsel & 2) ? uBA : uAA,  vCA = (tsel & 2) ? uAA : uBA; \
    float uCB = (tsel & 2) ? uBB : uAB,  vCB = (tsel & 2) ? uAB : uBB; \
    DPPADDV(uCA, vCA, 0x4E)  DPPADDV(uCB, vCB, 0x4E) \
    DPPSTEP(uCA, 0x141)      DPPSTEP(uCB, 0x141) \
    float EA = __builtin_amdgcn_exp2f(uCA); \
    float EB = __builtin_amdgcn_exp2f(uCB); \
    float rA = __builtin_amdgcn_rcpf(1.f + EA); \
    float rB = __builtin_amdgcn_rcpf(1.f + EB); \
    int aiA = __float_as_int(fmaf(mC, rA, aC)); \
    int aiB = __float_as_int(fmaf(mC, rB, aC)); \
    QBCAST(siA, aiA, 0x00) QBCAST(siB, aiB, 0x00) \
    QBCAST(sfA, aiA, 0x55) QBCAST(sfB, aiB, 0x55) \
    QBCAST(tgA, aiA, 0xAA) QBCAST(tgB, aiB, 0xAA) \
    QBCAST(soA, aiA, 0xFF) QBCAST(soB, aiB, 0xFF) \
    cUA = fmaf(sfA, cUA, siA * tgA); \
    cUB = fmaf(sfB, cUB, siB * tgB); \
    float eA2 = __builtin_amdgcn_exp2f(SPOS * cUA); \
    float eB2 = __builtin_amdgcn_exp2f(SPOS * cUB); \
    float tA2 = fmaf(-2.f, __builtin_amdgcn_rcpf(1.f + eA2), 1.f); \
    float tB2 = fmaf(-2.f, __builtin_amdgcn_rcpf(1.f + eB2), 1.f); \
    float hNA = soA * tA2; \
    float hNB = soB * tB2; \
    STA

// Packed dual LSTM step, role 0. POFFF = float offset of read buffer (0/192).
#define STEP0P(POFFF, XTA, XTB) { \
    const float4* hp = reinterpret_cast<const float4*>(hs2p + (POFFF)) + 6 * s; \
    float4 hq0=hp[0], hq1=hp[1], hq2=hp[2], hq3=hp[3], hq4=hp[4], hq5=hp[5]; \
    v2f giP = { fmaf(wiI,(XTA),bbI), fmaf(wiI,(XTB),bbI) }; \
    v2f gfP = { fmaf(wiF,(XTA),bbF), fmaf(wiF,(XTB),bbF) }; \
    v2f ggP = { fmaf(wiG,(XTA),bbG), fmaf(wiG,(XTB),bbG) }; \
    v2f goP = { fmaf(wiO,(XTA),bbO), fmaf(wiO,(XTB),bbO) }; \
    HUNPACK() \
    MVALL() \
    float giA=giP.x, gfA=gfP.x, ggA=ggP.x, goA=goP.x; \
    float giB=giP.y, gfB=gfP.y, ggB=ggP.y, goB=goP.y; \
    GT2( \
      if (w0l) { \
        float2 hw; hw.x = hNA; hw.y = hNB; \
        *reinterpret_cast<float2*>(hs2p + ((POFFF) ^ 192) + 2 * e) = hw; \
        *hobpA = hNA; *hobpB = hNB; } \
      hobpA += HDIM; hobpB += HDIM; ) }

// Packed dual LSTM step, role 2. Q0={iA,iB,fA,fB}, Q1={gA,gB,oA,oB}.
#define STEP2P(POFFF, Q0, Q1) { \
    const float4* hp = reinterpret_cast<const float4*>(hs2p + (POFFF)) + 6 * s; \
    float4 hq0=hp[0], hq1=hp[1], hq2=hp[2], hq3=hp[3], hq4=hp[4], hq5=hp[5]; \
    v2f giP = { (Q0).x, (Q0).y }; \
    v2f gfP = { (Q0).z, (Q0).w }; \
    v2f ggP = { (Q1).x, (Q1).y }; \
    v2f goP = { (Q1).z, (Q1).w }; \
    HUNPACK() \
    MVALL() \
    float giA=giP.x, gfA=gfP.x, ggA=ggP.x, goA=goP.x; \
    float giB=giP.y, gfB=gfP.y, ggB=ggP.y, goB=goP.y; \
    GT2( \
      if (w0l) { \
        float2 hw; hw.x = hNA; hw.y = hNB; \
        *reinterpret_cast<float2*>(hs2p + ((POFFF) ^ 192) + 2 * e) = hw; \
        *h1pA = hNA; *h1pB = hNB; } \
      h1pA += HDIM; h1pB += HDIM; ) }

#define WAIT_GE(PTR, VAL) \
    while (__hip_atomic_load((PTR), __ATOMIC_ACQUIRE, __HIP_MEMORY_SCOPE_AGENT) < (VAL)) \
        __builtin_amdgcn_s_sleep(2);

#define SIGNAL(PTR, VAL) \
    __hip_atomic_store((PTR), (VAL), __ATOMIC_RELEASE, __HIP_MEMORY_SCOPE_AGENT);

__global__ void init_flags(int* flags) {
    if (threadIdx.x < 64) flags[threadIdx.x] = 0;
}

// ---------------------------------------------------------------------------
// 16 blocks, 4 roles x 4 pair-blocks. Pair pr handles batches bA=2pr, bB=2pr+1.
// The two recurrences are PACKED into register pairs (v_pk_fma_f32 / paired
// scalar FMAs) so the compiler CANNOT serialize them (R11 lesson: source
// interleave alone is reorderable; VGPR=72 proved re-serialization).
// h state in LDS is pair-interleaved {hA[c],hB[c]}; xp ring pair-interleaved.
//   role 0: packed dual L0 scan -> h0buf, flag0[pr]
//   role 1: xp worker, both batches -> pair-interleaved xp ring, flag1[pr]
//   role 2: packed dual L1 scan -> h1 ring, flag2[pr]
//   role 3: head, both batches -> out, flag3[pr]
// ---------------------------------------------------------------------------
__global__ void __launch_bounds__(768)
__attribute__((amdgpu_waves_per_eu(3, 3)))
lstm_pipe(const float* __restrict__ x,
          const float* __restrict__ Wih0, const float* __restrict__ Whh0, const float* __restrict__ b0v,
          const float* __restrict__ Wih1, const float* __restrict__ Whh1, const float* __restrict__ b1v,
          const float* __restrict__ h0v,  const float* __restrict__ c0v,
          const float* __restrict__ headw,const float* __restrict__ headb,
          float* __restrict__ h0buf, float* __restrict__ xpbuf, float* __restrict__ h1buf,
          int* flags, float* __restrict__ out)
{
    const int tid  = threadIdx.x;
    const int lane = tid & 63;
    const int e    = tid >> 3;     // element 0..95
    const int s    = tid & 7;      // 12-col segment 0..7
    const bool w0l = ((lane & 7) == 0);

    int* flag0 = flags;
    int* flag1 = flags + 8;
    int* flag2 = flags + 16;
    int* flag3 = flags + 24;

    __shared__ __align__(16) float hs2p[2 * 2 * HDIM];  // [dbuf][col][{A,B}]
    __shared__ __align__(16) float h_sh[32 * HDIM];
    __shared__ float ph_sh[2 * G4];          // tt-parity double buffer

    const int role = blockIdx.x >> 2;
    const int pr   = blockIdx.x & 3;
    const int bA   = 2 * pr;
    const int bB   = 2 * pr + 1;

    // mirror-symmetric gate index for the merged butterfly (loop-invariant):
    // quad 0 -> i,f,g,o ; quad 1 -> o,g,f,i
    const int tsel = (s & 3) ^ ((s & 4) ? 3 : 0);
    const float mC = (tsel == 2) ? -2.f : 1.f;
    const float aC = (tsel == 2) ?  1.f : 0.f;

    if (role == 0) {
        // =================== producer: packed dual L0 scan ===============
        WLOADPIN_P(Whh0)
        const float wiI = Wih0[e]      * (SNEG * 0.125f);
        const float wiF = Wih0[96 + e] * (SNEG * 0.125f);
        const float wiG = Wih0[192+ e] * (SPOS * 0.125f);
        const float wiO = Wih0[288+ e] * (SNEG * 0.125f);
        const float bbI = b0v[e]       * (SNEG * 0.125f);
        const float bbF = b0v[96 + e]  * (SNEG * 0.125f);
        const float bbG = b0v[192+ e]  * (SPOS * 0.125f);
        const float bbO = b0v[288+ e]  * (SNEG * 0.125f);

        float cUA = c0v[e], cUB = c0v[e];
        if (w0l) { float2 hw; hw.x = h0v[e]; hw.y = h0v[e];
                   *reinterpret_cast<float2*>(hs2p + 2 * e) = hw; }
        __syncthreads();

        const float* xbA = x + (size_t)bA * LSEQ;
        const float* xbB = x + (size_t)bB * LSEQ;
        float* hobpA = h0buf + (size_t)bA * LSEQ * HDIM + e;
        float* hobpB = h0buf + (size_t)bB * LSEQ * HDIM + e;

        float4 xAA = *reinterpret_cast<const float4*>(xbA);   // t = 0..3
        float4 xAB = *reinterpret_cast<const float4*>(xbB);

#pragma unroll 1
        for (int gI = 0; gI < LSEQ / 8; ++gI) {
            float4 xBA = *reinterpret_cast<const float4*>(xbA + gI * 8 + 4);
            float4 xBB = *reinterpret_cast<const float4*>(xbB + gI * 8 + 4);
            STEP0P(0,   xAA.x, xAB.x) BARL();
            STEP0P(192, xAA.y, xAB.y) BARL();
            STEP0P(0,   xAA.z, xAB.z) BARL();
            STEP0P(192, xAA.w, xAB.w) BARL();
            const int nOff = ((gI + 1) * 8 < LSEQ) ? (gI + 1) * 8 : LSEQ - 8;
            float4 xAnA = *reinterpret_cast<const float4*>(xbA + nOff);
            float4 xAnB = *reinterpret_cast<const float4*>(xbB + nOff);
            STEP0P(0,   xBA.x, xBB.x) BARL();
            STEP0P(192, xBA.y, xBB.y) BARL();
            STEP0P(0,   xBA.z, xBB.z) BARL();
            STEP0P(192, xBA.w, xBB.w)
            xAA = xAnA; xAB = xAnB;
            if (((gI + 1) & 127) == 0) {      // t+1 = 8(gI+1) ≡ 0 mod TCH
                __threadfence();
                __syncthreads();
                if (tid == 0) SIGNAL(&flag0[pr], (gI + 1) >> 7)
            } else {
                BARL();
            }
        }
    } else if (role == 1) {
        // =================== xp worker (both batches/chunk) ===============
        const bool halfx = (tid >= G4);
        const int  g     = halfx ? tid - G4 : tid;
        // pair-interleaved (t, e, gate, {A,B}) layout: batch offset added at write
        const int  dstoff = (g % 96) * 8 + (g / 96) * 2;
        const float gsc  = (((g / 96) == 2) ? SPOS : SNEG) * 0.125f;
        const float4* Wxp = reinterpret_cast<const float4*>(Wih1 + (size_t)g * HDIM + (halfx ? 48 : 0));
        const float xbias = halfx ? 0.f : b1v[g] * gsc;

        float4 q0=Wxp[0],q1=Wxp[1],q2=Wxp[2],q3=Wxp[3],q4=Wxp[4],q5=Wxp[5],
               q6=Wxp[6],q7=Wxp[7],q8=Wxp[8],q9=Wxp[9],q10=Wxp[10],q11=Wxp[11];
        SC4(q0,gsc) SC4(q1,gsc) SC4(q2,gsc)  SC4(q3,gsc) SC4(q4,gsc)  SC4(q5,gsc)
        SC4(q6,gsc) SC4(q7,gsc) SC4(q8,gsc)  SC4(q9,gsc) SC4(q10,gsc) SC4(q11,gsc)
        PIN4x3(q0,q1,q2) PIN4x3(q3,q4,q5) PIN4x3(q6,q7,q8) PIN4x3(q9,q10,q11)

#pragma unroll 1
        for (int k = 0; k < NCH; ++k) {
            if (tid == 0) {
                WAIT_GE(&flag0[pr], k + 1)
                if (k >= 2) WAIT_GE(&flag2[pr], k - 1)
            }
            __syncthreads();
            __threadfence();

            float* xpd = xpbuf + ((size_t)pr * 2 + (k & 1)) * ((size_t)TCH * G4 * 2);

#pragma unroll 1
            for (int bb = 0; bb < 2; ++bb) {
                const int b = 2 * pr + bb;
                const float* hsrc = h0buf + (size_t)b * LSEQ * HDIM + (size_t)k * TCH * HDIM;

#pragma unroll 1
                for (int t0 = 0; t0 < TCH; t0 += 32) {
                    // 32*96 floats = exactly one float4 per thread
                    reinterpret_cast<float4*>(h_sh)[tid] =
                        reinterpret_cast<const float4*>(hsrc + (size_t)t0 * HDIM)[tid];
                    BARL();
#pragma unroll 1
                    for (int tt = 0; tt < 32; ++tt) {
                        const float4* h4 = reinterpret_cast<const float4*>(
                            h_sh + tt * HDIM + (halfx ? 48 : 0));
                        float a0 = xbias, a1 = 0.f, a2 = 0.f, a3 = 0.f;
                        float4 hv;
                        hv=h4[0];  a0=fmaf(q0.x, hv.x,a0); a1=fmaf(q0.y, hv.y,a1); a2=fmaf(q0.z, hv.z,a2); a3=fmaf(q0.w, hv.w,a3);
                        hv=h4[1];  a0=fmaf(q1.x, hv.x,a0); a1=fmaf(q1.y, hv.y,a1); a2=fmaf(q1.z, hv.z,a2); a3=fmaf(q1.w, hv.w,a3);
                        hv=h4[2];  a0=fmaf(q2.x, hv.x,a0); a1=fmaf(q2.y, hv.y,a1); a2=fmaf(q2.z, hv.z,a2); a3=fmaf(q2.w, hv.w,a3);
                        hv=h4[3];  a0=fmaf(q3.x, hv.x,a0); a1=fmaf(q3.y, hv.y,a1); a2=fmaf(q3.z, hv.z,a2); a3=fmaf(q3.w, hv.w,a3);
                        hv=h4[4];  a0=fmaf(q4.x, hv.x,a0); a1=fmaf(q4.y, hv.y,a1); a2=fmaf(q4.z, hv.z,a2); a3=fmaf(q4.w, hv.w,a3);
                        hv=h4[5];  a0=fmaf(q5.x, hv.x,a0); a1=fmaf(q5.y, hv.y,a1); a2=fmaf(q5.z, hv.z,a2); a3=fmaf(q5.w, hv.w,a3);
                        hv=h4[6];  a0=fmaf(q6.x, hv.x,a0); a1=fmaf(q6.y, hv.y,a1); a2=fmaf(q6.z, hv.z,a2); a3=fmaf(q6.w, hv.w,a3);
                        hv=h4[7];  a0=fmaf(q7.x, hv.x,a0); a1=fmaf(q7.y, hv.y,a1); a2=fmaf(q7.z, hv.z,a2); a3=fmaf(q7.w, hv.w,a3);
                        hv=h4[8];  a0=fmaf(q8.x, hv.x,a0); a1=fmaf(q8.y, hv.y,a1); a2=fmaf(q8.z, hv.z,a2); a3=fmaf(q8.w, hv.w,a3);
                        hv=h4[9];  a0=fmaf(q9.x, hv.x,a0); a1=fmaf(q9.y, hv.y,a1); a2=fmaf(q9.z, hv.z,a2); a3=fmaf(q9.w, hv.w,a3);
                        hv=h4[10]; a0=fmaf(q10.x,hv.x,a0); a1=fmaf(q10.y,hv.y,a1); a2=fmaf(q10.z,hv.z,a2); a3=fmaf(q10.w,hv.w,a3);
                        hv=h4[11]; a0=fmaf(q11.x,hv.x,a0); a1=fmaf(q11.y,hv.y,a1); a2=fmaf(q11.z,hv.z,a2); a3=fmaf(q11.w,hv.w,a3);
                        float part = (a0 + a1) + (a2 + a3);
                        float* ph2 = ph_sh + ((tt & 1) ? G4 : 0);   // parity dbuf
                        if (halfx) ph2[g] = part;
                        BARL();
                        if (!halfx) xpd[(size_t)(t0 + tt) * (G4 * 2) + dstoff + bb] = part + ph2[g];
                    }
                    BARL();   // protect h_sh + ph slot reuse before next stage
                }
            }
            __threadfence();
            __syncthreads();
            if (tid == 0) SIGNAL(&flag1[pr], k + 1)
        }
    } else if (role == 2) {
        // =================== consumer: packed dual L1 scan ===============
        WLOADPIN_P(Whh1)

        float cUA = c0v[HDIM + e], cUB = c0v[HDIM + e];
        if (w0l) { float2 hw; hw.x = h0v[HDIM + e]; hw.y = h0v[HDIM + e];
                   *reinterpret_cast<float2*>(hs2p + 2 * e) = hw; }
        __syncthreads();

#pragma unroll 1
        for (int k = 0; k < NCH; ++k) {
            if (tid == 0) {
                WAIT_GE(&flag1[pr], k + 1)
                if (k >= 2) WAIT_GE(&flag3[pr], k - 1)
            }
            __syncthreads();
            __threadfence();

            const float4* xq = reinterpret_cast<const float4*>(
                xpbuf + ((size_t)pr * 2 + (k & 1)) * ((size_t)TCH * G4 * 2)) + 2 * e;
            float* h1pA = h1buf + ((size_t)bA * 2 + (k & 1)) * TCH * HDIM + e;
            float* h1pB = h1buf + ((size_t)bB * 2 + (k & 1)) * TCH * HDIM + e;

            // 4-step rotation: f{0..3}{a,b} hold steps t..t+3 (192 float4/step)
            float4 f0a = xq[0],       f0b = xq[1];
            float4 f1a = xq[192],     f1b = xq[193];
            float4 f2a = xq[2 * 192], f2b = xq[2 * 192 + 1];
            float4 f3a = xq[3 * 192], f3b = xq[3 * 192 + 1];

#pragma unroll 1
            for (int gI = 0; gI < TCH / 8; ++gI) {
                const float4* xg = xq + (size_t)gI * 8 * 192;
                STEP2P(0,   f0a, f0b) f0a = xg[4 * 192]; f0b = xg[4 * 192 + 1]; BARL();
                STEP2P(192, f1a, f1b) f1a = xg[5 * 192]; f1b = xg[5 * 192 + 1]; BARL();
                STEP2P(0,   f2a, f2b) f2a = xg[6 * 192]; f2b = xg[6 * 192 + 1]; BARL();
                STEP2P(192, f3a, f3b) f3a = xg[7 * 192]; f3b = xg[7 * 192 + 1]; BARL();
                const float4* xn = xq + (size_t)((gI + 1 < TCH / 8) ? (gI + 1) * 8 : TCH - 8) * 192;
                STEP2P(0,   f0a, f0b) f0a = xn[0];       f0b = xn[1];           BARL();
                STEP2P(192, f1a, f1b) f1a = xn[192];     f1b = xn[193];         BARL();
                STEP2P(0,   f2a, f2b) f2a = xn[2 * 192]; f2b = xn[2 * 192 + 1]; BARL();
                STEP2P(192, f3a, f3b) f3a = xn[3 * 192]; f3b = xn[3 * 192 + 1]; BARL();
            }
            __threadfence();
            __syncthreads();
            if (tid == 0) SIGNAL(&flag2[pr], k + 1)
        }
    } else {
        // =================== head (both batches/chunk) ===================
        const float hb = headb[0];
        float4 wv[24];
#pragma unroll
        for (int j = 0; j < 24; ++j) wv[j] = reinterpret_cast<const float4*>(headw)[j];

#pragma unroll 1
        for (int k = 0; k < NCH; ++k) {
            if (tid == 0) WAIT_GE(&flag2[pr], k + 1)
            __syncthreads();
            __threadfence();

#pragma unroll 1
            for (int bb = 0; bb < 2; ++bb) {
                const int b = 2 * pr + bb;
                const float* h1c = h1buf + ((size_t)b * 2 + (k & 1)) * TCH * HDIM;
                for (int t = tid; t < TCH; t += 768) {
                    const float4* hp = reinterpret_cast<const float4*>(h1c + (size_t)t * HDIM);
                    float s2 = 0.f;
#pragma unroll
                    for (int j = 0; j < 24; ++j) {
                        float4 a = hp[j], bwv = wv[j];
                        s2 = fmaf(a.x, bwv.x, s2); s2 = fmaf(a.y, bwv.y, s2);
                        s2 = fmaf(a.z, bwv.z, s2); s2 = fmaf(a.w, bwv.w, s2);
                    }
                    out[(size_t)b * LSEQ + (size_t)k * TCH + t] = s2 + hb;
                }
            }
            __threadfence();
            __syncthreads();
            if (tid == 0) SIGNAL(&flag3[pr], k + 1)
        }
    }
}

// ---------------------------------------------------------------------------
extern "C" void kernel_launch(void* const* d_in, const int* in_sizes, int n_in,
                              void* d_out, int out_size, void* d_ws, size_t ws_size,
                              hipStream_t stream)
{
    const float* x     = (const float*)d_in[0];
    const float* Wih0  = (const float*)d_in[1];
    const float* Whh0  = (const float*)d_in[2];
    const float* b0    = (const float*)d_in[3];
    const float* Wih1  = (const float*)d_in[4];
    const float* Whh1  = (const float*)d_in[5];
    const float* b1    = (const float*)d_in[6];
    const float* h0    = (const float*)d_in[7];
    const float* c0    = (const float*)d_in[8];
    const float* headw = (const float*)d_in[9];
    const float* headb = (const float*)d_in[10];
    float* out = (float*)d_out;

    char* ws = (char*)d_ws;
    const size_t h0bytes = (size_t)BATCH * LSEQ * HDIM * sizeof(float);    // 100.7 MB
    const size_t xpbytes = (size_t)BATCH * 2 * TCH * G4 * sizeof(float);   // 25.2 MB (4 pairs x 2 x TCH x 768)
    const size_t h1bytes = (size_t)BATCH * 2 * TCH * HDIM * sizeof(float); // 6.3 MB

    float* h0buf = (float*)ws;
    float* xpbuf = (float*)(ws + h0bytes);
    float* h1buf = (float*)(ws + h0bytes + xpbytes);
    int*   flags = (int*)  (ws + h0bytes + xpbytes + h1bytes);

    init_flags<<<1, 64, 0, stream>>>(flags);
    lstm_pipe<<<16, 768, 0, stream>>>(x, Wih0, Whh0, b0, Wih1, Whh1, b1,
                                      h0, c0, headw, headb,
                                      h0buf, xpbuf, h1buf, flags, out);
}

// Round 13
// 14177.206 us; speedup vs baseline: 2.2515x; 2.2515x over previous
//
#include <hip/hip_runtime.h>

#define HDIM 96
#define G4   384
#define LSEQ 32768
#define BATCH 8
#define TCH   1024
#define NCH   (LSEQ / TCH)

#define L2E  1.4426950408889634f
#define SNEG (-L2E)        /* sigmoid gates: exp(-x) = exp2(SNEG*x) */
#define SPOS (2.0f * L2E)  /* tanh gates:    exp(2x) = exp2(SPOS*x) */

__device__ __forceinline__ float tanh_(float x) {    // raw argument (c state)
    // overflow-safe: exp2 -> inf => rcp -> 0 => tanh -> 1. NO fused form here.
    return fmaf(-2.f, __builtin_amdgcn_rcpf(1.f + __builtin_amdgcn_exp2f(SPOS * x)), 1.f);
}

// DPP helpers (VALU pipe, zero DS usage).
#define DPPSTEP(v, CTRL) { \
    int t_ = __builtin_amdgcn_update_dpp(0, __float_as_int(v), CTRL, 0xF, 0xF, true); \
    v += __int_as_float(t_); }
#define DPPADDV(u, v, CTRL) { \
    int t_ = __builtin_amdgcn_update_dpp(0, __float_as_int(v), CTRL, 0xF, 0xF, true); \
    u += __int_as_float(t_); }

// quad_perm broadcast: all lanes of each quad read quad-lane L of src.
#define QBCAST(DST, SRCI, CTRL) \
    float DST = __int_as_float(__builtin_amdgcn_update_dpp(0, (SRCI), (CTRL), 0xF, 0xF, true));

// Lite barrier: LDS ordering only; global ops stay in flight.
#define BARL() asm volatile("s_waitcnt lgkmcnt(0)\n\ts_barrier" ::: "memory")

#define PIN4x3(A,B,C) asm volatile("" : \
  "+v"(A.x),"+v"(A.y),"+v"(A.z),"+v"(A.w), \
  "+v"(B.x),"+v"(B.y),"+v"(B.z),"+v"(B.w), \
  "+v"(C.x),"+v"(C.y),"+v"(C.z),"+v"(C.w));

#define SC4(V, S) { V.x *= (S); V.y *= (S); V.z *= (S); V.w *= (S); }

// Thread owns all 4 gate rows of element e x cols [12s, 12s+12).
// Weights pre-scaled per gate for exp2-direct activations. f32 scalar MVK
// with 4-gate interleave (ILP=4) is the proven structure (R3: pk_fma
// regressed; R7: fdot2 fp16 regressed — both extended the latency chain;
// R10-R12: batch-pairing cannot reduce wall time on a latency-bound scan).
#define WLOADPIN(W) \
    const float4* pI = reinterpret_cast<const float4*>((W) + (size_t)e        * HDIM + 12*s); \
    const float4* pF = reinterpret_cast<const float4*>((W) + (size_t)(96 + e) * HDIM + 12*s); \
    const float4* pG = reinterpret_cast<const float4*>((W) + (size_t)(192+ e) * HDIM + 12*s); \
    const float4* pO = reinterpret_cast<const float4*>((W) + (size_t)(288+ e) * HDIM + 12*s); \
    float4 wI0=pI[0], wI1=pI[1], wI2=pI[2]; \
    float4 wF0=pF[0], wF1=pF[1], wF2=pF[2]; \
    float4 wG0=pG[0], wG1=pG[1], wG2=pG[2]; \
    float4 wO0=pO[0], wO1=pO[1], wO2=pO[2]; \
    SC4(wI0,SNEG) SC4(wI1,SNEG) SC4(wI2,SNEG) \
    SC4(wF0,SNEG) SC4(wF1,SNEG) SC4(wF2,SNEG) \
    SC4(wG0,SPOS) SC4(wG1,SPOS) SC4(wG2,SPOS) \
    SC4(wO0,SNEG) SC4(wO1,SNEG) SC4(wO2,SNEG) \
    PIN4x3(wI0,wI1,wI2) PIN4x3(wF0,wF1,wF2) PIN4x3(wG0,wG1,wG2) PIN4x3(wO0,wO1,wO2)

#define MVK(n, hv) \
  gi=fmaf(wI##n.x,hv.x,gi); gi=fmaf(wI##n.y,hv.y,gi); gi=fmaf(wI##n.z,hv.z,gi); gi=fmaf(wI##n.w,hv.w,gi); \
  gf=fmaf(wF##n.x,hv.x,gf); gf=fmaf(wF##n.y,hv.y,gf); gf=fmaf(wF##n.z,hv.z,gf); gf=fmaf(wF##n.w,hv.w,gf); \
  gg=fmaf(wG##n.x,hv.x,gg); gg=fmaf(wG##n.y,hv.y,gg); gg=fmaf(wG##n.z,hv.z,gg); gg=fmaf(wG##n.w,hv.w,gg); \
  go=fmaf(wO##n.x,hv.x,go); go=fmaf(wO##n.y,hv.y,go); go=fmaf(wO##n.z,hv.z,go); go=fmaf(wO##n.w,hv.w,go);

// Merged transposing reduction + batched activation tail, MIRROR-SYMMETRIC
// (verified bitwise-identical to RED8, R9). Target layout
// t(s) = (s&3) ^ (s&4 ? 3 : 0)  ->  quad0: i,f,g,o; quad1: o,g,f,i.
// Lane 7-s carries the SAME gate as lane s so the 0x141 mirror completes
// each gate's 8-sum. Lane 0's add tree is bitwise-identical to RED8.
// Quad 1's activations are order-swapped -> cU garbage in lanes 4..7,
// harmless: only lane s==0 writes hN; accumulators re-init each step.
#define GATES_TAIL(DEST_STORE) \
    float uA = (tsel & 1) ? gf : gi,  vA = (tsel & 1) ? gi : gf; \
    float uB = (tsel & 1) ? go : gg,  vB = (tsel & 1) ? gg : go; \
    DPPADDV(uA, vA, 0xB1)  DPPADDV(uB, vB, 0xB1) \
    float uC = (tsel & 2) ? uB : uA,  vC = (tsel & 2) ? uA : uB; \
    DPPADDV(uC, vC, 0x4E) \
    DPPSTEP(uC, 0x141) \
    float E_ = __builtin_amdgcn_exp2f(uC); \
    float r_ = __builtin_amdgcn_rcpf(1.f + E_); \
    int ai = __float_as_int(fmaf(mC, r_, aC)); \
    QBCAST(si, ai, 0x00) \
    QBCAST(sf, ai, 0x55) \
    QBCAST(tg, ai, 0xAA) \
    QBCAST(so, ai, 0xFF) \
    cU = fmaf(sf, cU, si * tg); \
    float hN = so * tanh_(cU); \
    DEST_STORE

// One LSTM step, role 0. RO = LDS read offset (0/96, compile-time).
// x-term folded into accumulator INIT (pre-scaled by gate-const/8; the
// 8-lane butterfly sums 8 identical copies back — exact, powers of two).
#define STEP0(RO, XT) { \
    const float4* hp = reinterpret_cast<const float4*>(hs + (RO) + 12 * s); \
    float4 hv0 = hp[0], hv1 = hp[1], hv2 = hp[2]; \
    float gi = fmaf(wiI, (XT), bbI); \
    float gf = fmaf(wiF, (XT), bbF); \
    float gg = fmaf(wiG, (XT), bbG); \
    float go = fmaf(wiO, (XT), bbO); \
    MVK(0, hv0) MVK(1, hv1) MVK(2, hv2) \
    GATES_TAIL( \
      if (w0l) { hs[((RO) ^ HDIM) + e] = hN; *hobp = hN; } \
      hobp += HDIM; ) }

// One LSTM step, role 2. xp (pre-scaled by gate-const/8 at role 1) folds
// into the accumulator init; butterfly restores the full value.
#define STEP2(RO, XPV) { \
    const float4* hp = reinterpret_cast<const float4*>(hs + (RO) + 12 * s); \
    float4 hv0 = hp[0], hv1 = hp[1], hv2 = hp[2]; \
    float gi = (XPV).x, gf = (XPV).y, gg = (XPV).z, go = (XPV).w; \
    MVK(0, hv0) MVK(1, hv1) MVK(2, hv2) \
    GATES_TAIL( \
      if (w0l) { hs[((RO) ^ HDIM) + e] = hN; *h1p = hN; } \
      h1p += HDIM; ) }

#define WAIT_GE(PTR, VAL) \
    while (__hip_atomic_load((PTR), __ATOMIC_ACQUIRE, __HIP_MEMORY_SCOPE_AGENT) < (VAL)) \
        __builtin_amdgcn_s_sleep(2);

#define SIGNAL(PTR, VAL) \
    __hip_atomic_store((PTR), (VAL), __ATOMIC_RELEASE, __HIP_MEMORY_SCOPE_AGENT);

__global__ void init_flags(int* flags) {
    if (threadIdx.x < 64) flags[threadIdx.x] = 0;
}

// ---------------------------------------------------------------------------
// 32 blocks, 4 roles:
//   0..7   producer : L0 scan (DPP core, x8 unroll) -> h0buf, flag0 per chunk
//   8..15  xp worker: flag0 -> xp ring depth 2 in (t,e,gate)-float4, flag1
//   16..23 consumer : flag1 -> L1 scan (DPP core, x8 unroll) -> h1 ring, flag2
//   24..31 head     : flag2 -> out, flag3 (h1 slot reuse)
// Converged structure: step = 1039 cyc = ~600 per-SIMD issue + ~340
// irreducible latency (post-barrier LDS wait + serial activation tail +
// barrier). Decomposition floor ~940; the per-step all-wave barrier is
// semantically required (all-to-all h dependency).
// ---------------------------------------------------------------------------
__global__ void __launch_bounds__(768)
__attribute__((amdgpu_waves_per_eu(3, 3)))
lstm_pipe(const float* __restrict__ x,
          const float* __restrict__ Wih0, const float* __restrict__ Whh0, const float* __restrict__ b0v,
          const float* __restrict__ Wih1, const float* __restrict__ Whh1, const float* __restrict__ b1v,
          const float* __restrict__ h0v,  const float* __restrict__ c0v,
          const float* __restrict__ headw,const float* __restrict__ headb,
          float* __restrict__ h0buf, float* __restrict__ xpbuf, float* __restrict__ h1buf,
          int* flags, float* __restrict__ out)
{
    const int tid  = threadIdx.x;
    const int lane = tid & 63;
    const int e    = tid >> 3;     // element 0..95
    const int s    = tid & 7;      // 12-col segment 0..7
    const bool w0l = ((lane & 7) == 0);

    int* flag0 = flags;
    int* flag1 = flags + 8;
    int* flag2 = flags + 16;
    int* flag3 = flags + 24;

    __shared__ __align__(16) float hs[2 * HDIM];
    __shared__ __align__(16) float h_sh[32 * HDIM];
    __shared__ float ph_sh[2 * G4];          // tt-parity double buffer

    const int role = blockIdx.x >> 3;
    const int bidx = blockIdx.x & 7;

    // mirror-symmetric gate index for the merged butterfly (loop-invariant):
    // quad 0 -> i,f,g,o ; quad 1 -> o,g,f,i
    const int tsel = (s & 3) ^ ((s & 4) ? 3 : 0);
    // map-fma constants: tanh map on the cell-gate lane (tsel==2)
    const float mC = (tsel == 2) ? -2.f : 1.f;
    const float aC = (tsel == 2) ?  1.f : 0.f;

    if (role == 0) {
        // =================== producer: L0 scan ===================
        WLOADPIN(Whh0)
        // input weights + bias pre-scaled by gate-const and 1/8 (butterfly
        // sums 8 identical copies back to full value — exact).
        const float wiI = Wih0[e]      * (SNEG * 0.125f);
        const float wiF = Wih0[96 + e] * (SNEG * 0.125f);
        const float wiG = Wih0[192+ e] * (SPOS * 0.125f);
        const float wiO = Wih0[288+ e] * (SNEG * 0.125f);
        const float bbI = b0v[e]       * (SNEG * 0.125f);
        const float bbF = b0v[96 + e]  * (SNEG * 0.125f);
        const float bbG = b0v[192+ e]  * (SPOS * 0.125f);
        const float bbO = b0v[288+ e]  * (SNEG * 0.125f);

        float cU = c0v[e];
        if (w0l) hs[e] = h0v[e];
        __syncthreads();

        const float* xb  = x + (size_t)bidx * LSEQ;
        float*       hobp = h0buf + (size_t)bidx * LSEQ * HDIM + e;

        float4 xA = *reinterpret_cast<const float4*>(xb);   // t = 0..3

#pragma unroll 1
        for (int gI = 0; gI < LSEQ / 8; ++gI) {
            float4 xB = *reinterpret_cast<const float4*>(xb + gI * 8 + 4);
            STEP0(0,    xA.x) BARL();
            STEP0(HDIM, xA.y) BARL();
            STEP0(0,    xA.z) BARL();
            STEP0(HDIM, xA.w) BARL();
            float4 xAn = *reinterpret_cast<const float4*>(
                xb + (((gI + 1) * 8 < LSEQ) ? (gI + 1) * 8 : LSEQ - 8));
            STEP0(0,    xB.x) BARL();
            STEP0(HDIM, xB.y) BARL();
            STEP0(0,    xB.z) BARL();
            STEP0(HDIM, xB.w)
            xA = xAn;
            if (((gI + 1) & 127) == 0) {      // t+1 = 8(gI+1) ≡ 0 mod TCH
                __threadfence();
                __syncthreads();
                if (tid == 0) SIGNAL(&flag0[bidx], (gI + 1) >> 7)
            } else {
                BARL();
            }
        }
    } else if (role == 1) {
        // =================== xp worker ===================
        const bool halfx = (tid >= G4);
        const int  g     = halfx ? tid - G4 : tid;
        const int  dstoff = (g % 96) * 4 + (g / 96);   // (e,gate) float4 layout
        // gate-const AND 1/8: role 2 folds xp into the accumulator init and
        // the 8-lane butterfly multiplies it back (exact, power of two).
        const float gsc  = (((g / 96) == 2) ? SPOS : SNEG) * 0.125f;
        const float4* Wxp = reinterpret_cast<const float4*>(Wih1 + (size_t)g * HDIM + (halfx ? 48 : 0));
        const float xbias = halfx ? 0.f : b1v[g] * gsc;

        float4 q0=Wxp[0],q1=Wxp[1],q2=Wxp[2],q3=Wxp[3],q4=Wxp[4],q5=Wxp[5],
               q6=Wxp[6],q7=Wxp[7],q8=Wxp[8],q9=Wxp[9],q10=Wxp[10],q11=Wxp[11];
        SC4(q0,gsc) SC4(q1,gsc) SC4(q2,gsc)  SC4(q3,gsc) SC4(q4,gsc)  SC4(q5,gsc)
        SC4(q6,gsc) SC4(q7,gsc) SC4(q8,gsc)  SC4(q9,gsc) SC4(q10,gsc) SC4(q11,gsc)
        PIN4x3(q0,q1,q2) PIN4x3(q3,q4,q5) PIN4x3(q6,q7,q8) PIN4x3(q9,q10,q11)

        const float* hsrcB = h0buf + (size_t)bidx * LSEQ * HDIM;

#pragma unroll 1
        for (int k = 0; k < NCH; ++k) {
            if (tid == 0) {
                WAIT_GE(&flag0[bidx], k + 1)
                if (k >= 2) WAIT_GE(&flag2[bidx], k - 1)
            }
            __syncthreads();
            __threadfence();

            const float* hsrc = hsrcB + (size_t)k * TCH * HDIM;
            float* xpd = xpbuf + ((size_t)bidx * 2 + (k & 1)) * TCH * G4;

#pragma unroll 1
            for (int t0 = 0; t0 < TCH; t0 += 32) {
                // 32*96 floats = exactly one float4 per thread
                reinterpret_cast<float4*>(h_sh)[tid] =
                    reinterpret_cast<const float4*>(hsrc + (size_t)t0 * HDIM)[tid];
                BARL();
#pragma unroll 1
                for (int tt = 0; tt < 32; ++tt) {
                    const float4* h4 = reinterpret_cast<const float4*>(
                        h_sh + tt * HDIM + (halfx ? 48 : 0));
                    float a0 = xbias, a1 = 0.f, a2 = 0.f, a3 = 0.f;
                    float4 hv;
                    hv=h4[0];  a0=fmaf(q0.x, hv.x,a0); a1=fmaf(q0.y, hv.y,a1); a2=fmaf(q0.z, hv.z,a2); a3=fmaf(q0.w, hv.w,a3);
                    hv=h4[1];  a0=fmaf(q1.x, hv.x,a0); a1=fmaf(q1.y, hv.y,a1); a2=fmaf(q1.z, hv.z,a2); a3=fmaf(q1.w, hv.w,a3);
                    hv=h4[2];  a0=fmaf(q2.x, hv.x,a0); a1=fmaf(q2.y, hv.y,a1); a2=fmaf(q2.z, hv.z,a2); a3=fmaf(q2.w, hv.w,a3);
                    hv=h4[3];  a0=fmaf(q3.x, hv.x,a0); a1=fmaf(q3.y, hv.y,a1); a2=fmaf(q3.z, hv.z,a2); a3=fmaf(q3.w, hv.w,a3);
                    hv=h4[4];  a0=fmaf(q4.x, hv.x,a0); a1=fmaf(q4.y, hv.y,a1); a2=fmaf(q4.z, hv.z,a2); a3=fmaf(q4.w, hv.w,a3);
                    hv=h4[5];  a0=fmaf(q5.x, hv.x,a0); a1=fmaf(q5.y, hv.y,a1); a2=fmaf(q5.z, hv.z,a2); a3=fmaf(q5.w, hv.w,a3);
                    hv=h4[6];  a0=fmaf(q6.x, hv.x,a0); a1=fmaf(q6.y, hv.y,a1); a2=fmaf(q6.z, hv.z,a2); a3=fmaf(q6.w, hv.w,a3);
                    hv=h4[7];  a0=fmaf(q7.x, hv.x,a0); a1=fmaf(q7.y, hv.y,a1); a2=fmaf(q7.z, hv.z,a2); a3=fmaf(q7.w, hv.w,a3);
                    hv=h4[8];  a0=fmaf(q8.x, hv.x,a0); a1=fmaf(q8.y, hv.y,a1); a2=fmaf(q8.z, hv.z,a2); a3=fmaf(q8.w, hv.w,a3);
                    hv=h4[9];  a0=fmaf(q9.x, hv.x,a0); a1=fmaf(q9.y, hv.y,a1); a2=fmaf(q9.z, hv.z,a2); a3=fmaf(q9.w, hv.w,a3);
                    hv=h4[10]; a0=fmaf(q10.x,hv.x,a0); a1=fmaf(q10.y,hv.y,a1); a2=fmaf(q10.z,hv.z,a2); a3=fmaf(q10.w,hv.w,a3);
                    hv=h4[11]; a0=fmaf(q11.x,hv.x,a0); a1=fmaf(q11.y,hv.y,a1); a2=fmaf(q11.z,hv.z,a2); a3=fmaf(q11.w,hv.w,a3);
                    float part = (a0 + a1) + (a2 + a3);
                    float* ph2 = ph_sh + ((tt & 1) ? G4 : 0);   // parity dbuf
                    if (halfx) ph2[g] = part;
                    BARL();
                    if (!halfx) xpd[(size_t)(t0 + tt) * G4 + dstoff] = part + ph2[g];
                }
                BARL();   // protect h_sh + ph slot reuse before next stage
            }
            __threadfence();
            __syncthreads();
            if (tid == 0) SIGNAL(&flag1[bidx], k + 1)
        }
    } else if (role == 2) {
        // =================== consumer: L1 scan ===================
        WLOADPIN(Whh1)

        float cU = c0v[HDIM + e];
        if (w0l) hs[e] = h0v[HDIM + e];
        __syncthreads();

#pragma unroll 1
        for (int k = 0; k < NCH; ++k) {
            if (tid == 0) {
                WAIT_GE(&flag1[bidx], k + 1)
                if (k >= 2) WAIT_GE(&flag3[bidx], k - 1)
            }
            __syncthreads();
            __threadfence();

            const float4* xq  = reinterpret_cast<const float4*>(
                xpbuf + ((size_t)bidx * 2 + (k & 1)) * TCH * G4) + e;
            float* h1p = h1buf + ((size_t)bidx * 2 + (k & 1)) * TCH * HDIM + e;

            float4 a0 = xq[0], a1 = xq[HDIM], a2 = xq[2 * HDIM], a3 = xq[3 * HDIM];

#pragma unroll 1
            for (int gI = 0; gI < TCH / 8; ++gI) {
                const float4* xg = xq + (size_t)gI * 8 * HDIM;
                float4 b0_, b1_, b2_, b3_;
                STEP2(0,    a0) b0_ = xg[4 * HDIM]; BARL();
                STEP2(HDIM, a1) b1_ = xg[5 * HDIM]; BARL();
                STEP2(0,    a2) b2_ = xg[6 * HDIM]; BARL();
                STEP2(HDIM, a3) b3_ = xg[7 * HDIM]; BARL();
                const float4* xn = xq + (size_t)((gI + 1 < TCH / 8) ? (gI + 1) * 8 : TCH - 8) * HDIM;
                STEP2(0,    b0_) a0 = xn[0];        BARL();
                STEP2(HDIM, b1_) a1 = xn[HDIM];     BARL();
                STEP2(0,    b2_) a2 = xn[2 * HDIM]; BARL();
                STEP2(HDIM, b3_) a3 = xn[3 * HDIM]; BARL();
            }
            __threadfence();
            __syncthreads();
            if (tid == 0) SIGNAL(&flag2[bidx], k + 1)
        }
    } else {
        // =================== head ===================
        const float hb = headb[0];
        float4 wv[24];
#pragma unroll
        for (int j = 0; j < 24; ++j) wv[j] = reinterpret_cast<const float4*>(headw)[j];

#pragma unroll 1
        for (int k = 0; k < NCH; ++k) {
            if (tid == 0) WAIT_GE(&flag2[bidx], k + 1)
            __syncthreads();
            __threadfence();

            const float* h1c = h1buf + ((size_t)bidx * 2 + (k & 1)) * TCH * HDIM;
            for (int t = tid; t < TCH; t += 768) {
                const float4* hp = reinterpret_cast<const float4*>(h1c + (size_t)t * HDIM);
                float s2 = 0.f;
#pragma unroll
                for (int j = 0; j < 24; ++j) {
                    float4 a = hp[j], b = wv[j];
                    s2 = fmaf(a.x, b.x, s2); s2 = fmaf(a.y, b.y, s2);
                    s2 = fmaf(a.z, b.z, s2); s2 = fmaf(a.w, b.w, s2);
                }
                out[(size_t)bidx * LSEQ + (size_t)k * TCH + t] = s2 + hb;
            }
            __threadfence();
            __syncthreads();
            if (tid == 0) SIGNAL(&flag3[bidx], k + 1)
        }
    }
}

// ---------------------------------------------------------------------------
extern "C" void kernel_launch(void* const* d_in, const int* in_sizes, int n_in,
                              void* d_out, int out_size, void* d_ws, size_t ws_size,
                              hipStream_t stream)
{
    const float* x     = (const float*)d_in[0];
    const float* Wih0  = (const float*)d_in[1];
    const float* Whh0  = (const float*)d_in[2];
    const float* b0    = (const float*)d_in[3];
    const float* Wih1  = (const float*)d_in[4];
    const float* Whh1  = (const float*)d_in[5];
    const float* b1    = (const float*)d_in[6];
    const float* h0    = (const float*)d_in[7];
    const float* c0    = (const float*)d_in[8];
    const float* headw = (const float*)d_in[9];
    const float* headb = (const float*)d_in[10];
    float* out = (float*)d_out;

    char* ws = (char*)d_ws;
    const size_t h0bytes = (size_t)BATCH * LSEQ * HDIM * sizeof(float);    // 100.7 MB
    const size_t xpbytes = (size_t)BATCH * 2 * TCH * G4 * sizeof(float);   // 25.2 MB
    const size_t h1bytes = (size_t)BATCH * 2 * TCH * HDIM * sizeof(float); // 6.3 MB

    float* h0buf = (float*)ws;
    float* xpbuf = (float*)(ws + h0bytes);
    float* h1buf = (float*)(ws + h0bytes + xpbytes);
    int*   flags = (int*)  (ws + h0bytes + xpbytes + h1bytes);

    init_flags<<<1, 64, 0, stream>>>(flags);
    lstm_pipe<<<32, 768, 0, stream>>>(x, Wih0, Whh0, b0, Wih1, Whh1, b1,
                                      h0, c0, headw, headb,
                                      h0buf, xpbuf, h1buf, flags, out);
}